// Round 1
// baseline (141.739 us; speedup 1.0000x reference)
//
#include <hip/hip_runtime.h>
#include <hip/hip_bf16.h>

// ---------------------------------------------------------------------------
// MMD loss:  mmd = (Sxx_offdiag)/(n(n-1)) + (Syy_offdiag)/(m(m-1)) - 2*Sxy/(n*m)
// with k(a,b) = exp(-max(|a-b|^2,0) / (2*sigma^2)), sigma^2 = D = 64  -> /128.
// N = M = 8192, D = 64.
//
// Strategy: bf16 MFMA (16x16x32) computes G = A.B^T with K=64 fully unrolled
// (2 chained MFMAs per 16x16 tile).  exp fused in epilogue:
//   k = exp( G/64 - (|a|^2/128 + |b|^2/128) ),  clamped to exp(<=0).
// kxx/kyy use symmetry: only j>i accumulated, doubled; trace excluded exactly.
// No LDS in the hot kernel: A-frags persist in regs, B-frags read from L2.
// ---------------------------------------------------------------------------

using short8 = __attribute__((ext_vector_type(8))) short;  // 8 bf16 (4 VGPRs)
using f32x4  = __attribute__((ext_vector_type(4))) float;  // 4 fp32

#define NROWS 8192
#define DDIM  64

// ---------------------------------------------------------------------------
// Prep: normalize X, cast X/Y to bf16, compute prescaled squared norms
// s = |row|^2 / 128 (from the bf16-rounded values, consistent with the MFMA).
// One wave per row; lane = dim.
// ---------------------------------------------------------------------------
__global__ __launch_bounds__(256) void mmd_prep(
    const float* __restrict__ z_seq, const float* __restrict__ pmean,
    const float* __restrict__ pstd, const float* __restrict__ z_prior,
    __hip_bfloat16* __restrict__ Xb, __hip_bfloat16* __restrict__ Yb,
    float* __restrict__ sxx, float* __restrict__ syy)
{
    const int tid  = threadIdx.x;
    const int lane = tid & 63;
    const int wid  = tid >> 6;
    const int row  = blockIdx.x * 4 + wid;   // 0..16383 (X rows then Y rows)

    float v;
    __hip_bfloat16* dst;
    float* sdst;
    int r;
    if (row < NROWS) {
        r = row;
        v = (z_seq[(size_t)r * DDIM + lane] - pmean[lane]) / pstd[lane];
        dst = Xb; sdst = sxx;
    } else {
        r = row - NROWS;
        v = z_prior[(size_t)r * DDIM + lane];
        dst = Yb; sdst = syy;
    }
    __hip_bfloat16 hb = __float2bfloat16(v);
    dst[(size_t)r * DDIM + lane] = hb;

    float vb = __bfloat162float(hb);
    float sq = vb * vb;
#pragma unroll
    for (int off = 32; off; off >>= 1) sq += __shfl_xor(sq, off, 64);
    if (lane == 0) sdst[r] = sq * (1.0f / 128.0f);
}

// ---------------------------------------------------------------------------
// Main: grid (32 jblocks, 64 iblocks, 3 modes). Block tile 128(i) x 256(j),
// 4 waves in 2x2, wave tile 64x128.  mode 0: XX (sym), 1: YY (sym), 2: XY.
// Each block writes one double partial (already x2 for symmetric modes).
// ---------------------------------------------------------------------------
__global__ __launch_bounds__(256) void mmd_main(
    const __hip_bfloat16* __restrict__ Xb, const __hip_bfloat16* __restrict__ Yb,
    const float* __restrict__ sxx, const float* __restrict__ syy,
    double* __restrict__ partials)
{
    const int mode = blockIdx.z;
    const int bj = blockIdx.x;          // 0..31  (256-wide j blocks)
    const int bi = blockIdx.y;          // 0..63  (128-tall i blocks)
    const int bid = mode * 2048 + bi * 32 + bj;

    const __hip_bfloat16* A;
    const __hip_bfloat16* Bp;
    const float* sa;
    const float* sb;
    if (mode == 0)      { A = Xb; Bp = Xb; sa = sxx; sb = sxx; }
    else if (mode == 1) { A = Yb; Bp = Yb; sa = syy; sb = syy; }
    else                { A = Xb; Bp = Yb; sa = sxx; sb = syy; }
    const bool sym = (mode < 2);

    const int tid  = threadIdx.x;
    const int lane = tid & 63;
    const int wid  = tid >> 6;
    const int quad = lane >> 4;
    const int l15  = lane & 15;

    const int iBlock = bi * 128;
    const int jBlock = bj * 256;

    // entire block strictly below the diagonal -> nothing to do
    if (sym && (jBlock + 256 <= iBlock)) {
        if (tid == 0) partials[bid] = 0.0;
        return;
    }

    const int i0 = iBlock + (wid >> 1) * 64;   // wave row origin
    const int j0 = jBlock + (wid & 1) * 128;   // wave col origin

    // Persistent A fragments: A[m=l15][k=quad*8+j], ks in {0,1} covers K=64.
    short8 af[4][2];
    f32x4  sx4[4];
#pragma unroll
    for (int mt = 0; mt < 4; ++mt) {
        const int ar = i0 + mt * 16 + l15;
#pragma unroll
        for (int ks = 0; ks < 2; ++ks)
            af[mt][ks] = *reinterpret_cast<const short8*>(
                A + (size_t)ar * DDIM + ks * 32 + quad * 8);
        // sxx for rows i0+mt*16+quad*4 .. +3 (C-layout rows for this lane)
        sx4[mt] = *reinterpret_cast<const f32x4*>(sa + i0 + mt * 16 + quad * 4);
    }

    constexpr float C2 = 1.0f / 64.0f;   // 2/(2*sigma^2)
    float lsum = 0.0f;

#pragma unroll
    for (int nt = 0; nt < 8; ++nt) {
        const int jt = j0 + nt * 16;
        if (sym && jt < i0) continue;    // all 4 mt-tiles below diagonal

        const size_t brow = (size_t)(jt + l15) * DDIM + quad * 8;
        short8 bf0 = *reinterpret_cast<const short8*>(Bp + brow);
        short8 bf1 = *reinterpret_cast<const short8*>(Bp + brow + 32);
        const float syv = sb[jt + l15];  // col j = jt + l15 for this lane

#pragma unroll
        for (int mt = 0; mt < 4; ++mt) {
            const int it = i0 + mt * 16;
            if (sym && jt < it) continue;          // tile strictly below diag

            f32x4 acc = {0.0f, 0.0f, 0.0f, 0.0f};
            acc = __builtin_amdgcn_mfma_f32_16x16x32_bf16(af[mt][0], bf0, acc, 0, 0, 0);
            acc = __builtin_amdgcn_mfma_f32_16x16x32_bf16(af[mt][1], bf1, acc, 0, 0, 0);

            if (sym && jt == it) {
                // diagonal tile: count only j > i (trace excluded exactly)
#pragma unroll
                for (int r = 0; r < 4; ++r) {
                    float t   = sx4[mt][r] + syv;
                    float arg = fminf(fmaf(acc[r], C2, -t), 0.0f);
                    float v   = __expf(arg);
                    lsum += (l15 > quad * 4 + r) ? v : 0.0f;
                }
            } else {
#pragma unroll
                for (int r = 0; r < 4; ++r) {
                    float t   = sx4[mt][r] + syv;
                    float arg = fminf(fmaf(acc[r], C2, -t), 0.0f);
                    lsum += __expf(arg);
                }
            }
        }
    }

    // wave reduce
#pragma unroll
    for (int off = 32; off; off >>= 1) lsum += __shfl_xor(lsum, off, 64);

    __shared__ float ws4[4];
    if (lane == 0) ws4[wid] = lsum;
    __syncthreads();
    if (tid == 0) {
        float tot = ws4[0] + ws4[1] + ws4[2] + ws4[3];
        if (sym) tot *= 2.0f;            // sum_{i!=j} = 2 * sum_{j>i}
        partials[bid] = (double)tot;
    }
}

// ---------------------------------------------------------------------------
// Finalize: reduce 6144 block partials with per-mode coefficients.
// ---------------------------------------------------------------------------
__global__ __launch_bounds__(256) void mmd_final(
    const double* __restrict__ partials, float* __restrict__ out)
{
    const int tid = threadIdx.x;
    const double cs = 1.0 / (8192.0 * 8191.0);       // modes 0,1
    const double cx = -2.0 / (8192.0 * 8192.0);      // mode 2

    double s = 0.0;
    for (int idx = tid; idx < 6144; idx += 256) {
        double c = (idx < 4096) ? cs : cx;
        s += partials[idx] * c;
    }
#pragma unroll
    for (int off = 32; off; off >>= 1) s += __shfl_xor(s, off, 64);

    __shared__ double wsum[4];
    const int lane = tid & 63, wid = tid >> 6;
    if (lane == 0) wsum[wid] = s;
    __syncthreads();
    if (tid == 0) {
        double mmd = wsum[0] + wsum[1] + wsum[2] + wsum[3];
        out[0] = (float)(mmd > 0.0 ? mmd : 0.0);
    }
}

// ---------------------------------------------------------------------------
extern "C" void kernel_launch(void* const* d_in, const int* in_sizes, int n_in,
                              void* d_out, int out_size, void* d_ws, size_t ws_size,
                              hipStream_t stream) {
    const float* z_seq   = (const float*)d_in[0];   // [16,512,64]
    const float* pmean   = (const float*)d_in[1];   // [64]
    const float* pstd    = (const float*)d_in[2];   // [64]
    const float* z_prior = (const float*)d_in[3];   // [8192,64]
    float* out = (float*)d_out;

    char* ws = (char*)d_ws;
    __hip_bfloat16* Xb = (__hip_bfloat16*)(ws);                    // 1 MB
    __hip_bfloat16* Yb = (__hip_bfloat16*)(ws + (1u << 20));       // 1 MB
    float* sxx = (float*)(ws + (2u << 20));                        // 32 KB
    float* syy = (float*)(ws + (2u << 20) + 32768);                // 32 KB
    double* partials = (double*)(ws + (2u << 20) + 65536);         // 48 KB

    mmd_prep<<<dim3(4096), dim3(256), 0, stream>>>(
        z_seq, pmean, pstd, z_prior, Xb, Yb, sxx, syy);
    mmd_main<<<dim3(32, 64, 3), dim3(256), 0, stream>>>(
        Xb, Yb, sxx, syy, partials);
    mmd_final<<<dim3(1), dim3(256), 0, stream>>>(partials, out);
}